// Round 11
// baseline (137.896 us; speedup 1.0000x reference)
//
#include <hip/hip_runtime.h>

// MaskPyramids R11: index chain = XLA reciprocal-multiply lowering:
//   lh = RNE( fl32( fl32(p * 0.005f) * H ) )
// Evidence trail: L1 failed identically under half-even (R2/3/5), down
// (R9), up (R10) -> ref's tie direction is per-instance MIXED -> the tie
// is not exact in ref arithmetic -> chained f32 rounding. R2 tested the
// fdiv chain (= mechanical numpy transliteration) and failed, so ref must
// be the jax/XLA output, and XLA rewrites divide-by-constant into
// multiply-by-reciprocal: c = fl32(1/200) = 0.005f (1-ulp different from
// fdiv at ~37% of p -> flips ties per-instance). Full folding p*0.5f is
// excluded (== half-even, R5). Two separate statements keep hipcc from
// reassociating (default precise fp).

#define G 28
#define CTR 13
#define ROW 53294          // 40000+10000+2500+625+169
#define PAIRS 26647        // ROW/2, one float2 per thread

template <int W, int BASE>
__device__ __forceinline__ float level_val(int r, int lh, int lw,
                                           const float* __restrict__ mask) {
  const int rr = r - BASE;
  const int i = rr / W;          // compile-time W -> magic multiply
  const int j = rr - i * W;
  const unsigned si = (unsigned)(CTR + i - lh);
  const unsigned sj = (unsigned)(CTR + j - lw);
  float v = 0.0f;
  if (si < (unsigned)G && sj < (unsigned)G) v = mask[si * G + sj];
  return v;
}

__global__ __launch_bounds__(256) void MaskPyramids_kernel(
    const int* __restrict__ pos, const float* __restrict__ mask,
    float* __restrict__ out) {
  const int inst = blockIdx.y;
  const int t = blockIdx.x * 256 + threadIdx.x;   // pair index within instance
  if (t >= PAIRS) return;

  // pos is uniform per block -> scalar loads/ALU.
  const int p0 = pos[2 * inst];
  const int p1 = pos[2 * inst + 1];

  // XLA chain: x = p * fl32(1/200); per-level lh = RNE(x * H).
  // 0.005f parses to the correctly-rounded fl32(1/200).
  const float x0 = (float)p0 * 0.005f;
  const float x1 = (float)p1 * 0.005f;

  const int lh0 = (int)rintf(x0 * 200.0f), lw0 = (int)rintf(x1 * 200.0f);
  const int lh1 = (int)rintf(x0 * 100.0f), lw1 = (int)rintf(x1 * 100.0f);
  const int lh2 = (int)rintf(x0 * 50.0f),  lw2 = (int)rintf(x1 * 50.0f);
  const int lh3 = (int)rintf(x0 * 25.0f),  lw3 = (int)rintf(x1 * 25.0f);
  const int lh4 = (int)rintf(x0 * 13.0f),  lw4 = (int)rintf(x1 * 13.0f);

  const int r0 = 2 * t;
  float v[2];
#pragma unroll
  for (int u = 0; u < 2; ++u) {
    const int r = r0 + u;
    if (r < 40000)      v[u] = level_val<200, 0>(r, lh0, lw0, mask);
    else if (r < 50000) v[u] = level_val<100, 40000>(r, lh1, lw1, mask);
    else if (r < 52500) v[u] = level_val<50, 50000>(r, lh2, lw2, mask);
    else if (r < 53125) v[u] = level_val<25, 52500>(r, lh3, lw3, mask);
    else                v[u] = level_val<13, 53125>(r, lh4, lw4, mask);
  }

  // inst*ROW even, r0 even -> 8-byte aligned float2 store.
  float2* dst = (float2*)(out + (size_t)inst * ROW + r0);
  *dst = make_float2(v[0], v[1]);
}

extern "C" void kernel_launch(void* const* d_in, const int* in_sizes, int n_in,
                              void* d_out, int out_size, void* d_ws, size_t ws_size,
                              hipStream_t stream) {
  const int* pos = (const int*)d_in[0];          // (512,2) int32
  const float* mask = (const float*)d_in[1];     // (28,28) float32
  float* out = (float*)d_out;                    // 512*53294 float32

  dim3 grid((PAIRS + 255) / 256, 512);           // 105 x 512 blocks
  MaskPyramids_kernel<<<grid, 256, 0, stream>>>(pos, mask, out);
}

// Round 12
// 116.736 us; speedup vs baseline: 1.1813x; 1.1813x over previous
//
#include <hip/hip_runtime.h>

// MaskPyramids R12: split into zero-fill + sparse window paint.
// Index chain (VERIFIED bit-exact in R11, absmax=0.0): XLA rcp-multiply:
//   x = (float)p * 0.005f;  lh_L = (int)rintf(x * (float)H_L)
// R11 single-pass kernel ran ~67 us (1.6 TB/s) - ALU-bound on the 5-way
// level chain + magic div per element. 98% of output is zero, so:
//   kernel 1: pure float4 zero-fill, 109 MB at fill speed (~18 us)
//   kernel 2: 512x5 blocks paint <=784 window cells each (~6.5 MB, ~3 us)
// Stream order guarantees paint lands after fill.

#define G 28
#define CTR 13
#define ROW 53294          // 40000+10000+2500+625+169 floats per instance
#define TOTAL_F4 6821632   // 512*53294/4, exact
#define FILL_BLOCKS 26647  // TOTAL_F4/256, exact

__global__ __launch_bounds__(256) void fill_zero_kernel(float4* __restrict__ out4) {
  const int idx = blockIdx.x * 256 + threadIdx.x;  // grid sized exactly
  out4[idx] = make_float4(0.f, 0.f, 0.f, 0.f);
}

template <int H, int W, int BASE>
__device__ __forceinline__ void paint(const float* __restrict__ mask,
                                      float* __restrict__ row,
                                      int lh, int lw) {
  // Iterate the 28x28 source window; map to level coords; skip clipped.
  for (int c = threadIdx.x; c < G * G; c += 256) {
    const int si = c / G;            // compile-time 28 -> magic multiply
    const int sj = c - si * G;
    const int i = lh + si - CTR;
    const int j = lw + sj - CTR;
    if ((unsigned)i < (unsigned)H && (unsigned)j < (unsigned)W)
      row[BASE + i * W + j] = mask[c];
  }
}

__global__ __launch_bounds__(256) void paint_kernel(
    const int* __restrict__ pos, const float* __restrict__ mask,
    float* __restrict__ out) {
  const int inst = blockIdx.x;       // 512
  const int lvl  = blockIdx.y;       // 5

  // pos uniform per block -> scalar loads.
  const int p0 = pos[2 * inst];
  const int p1 = pos[2 * inst + 1];
  // Verified XLA chain: two separate f32 multiplies, RNE.
  const float x0 = (float)p0 * 0.005f;
  const float x1 = (float)p1 * 0.005f;

  float* row = out + (size_t)inst * ROW;
  switch (lvl) {
    case 0: paint<200, 200, 0>(mask, row,
              (int)rintf(x0 * 200.0f), (int)rintf(x1 * 200.0f)); break;
    case 1: paint<100, 100, 40000>(mask, row,
              (int)rintf(x0 * 100.0f), (int)rintf(x1 * 100.0f)); break;
    case 2: paint<50, 50, 50000>(mask, row,
              (int)rintf(x0 * 50.0f), (int)rintf(x1 * 50.0f)); break;
    case 3: paint<25, 25, 52500>(mask, row,
              (int)rintf(x0 * 25.0f), (int)rintf(x1 * 25.0f)); break;
    default: paint<13, 13, 53125>(mask, row,
              (int)rintf(x0 * 13.0f), (int)rintf(x1 * 13.0f)); break;
  }
}

extern "C" void kernel_launch(void* const* d_in, const int* in_sizes, int n_in,
                              void* d_out, int out_size, void* d_ws, size_t ws_size,
                              hipStream_t stream) {
  const int* pos = (const int*)d_in[0];          // (512,2) int32
  const float* mask = (const float*)d_in[1];     // (28,28) float32
  float* out = (float*)d_out;                    // 512*53294 float32

  fill_zero_kernel<<<FILL_BLOCKS, 256, 0, stream>>>((float4*)out);
  dim3 pgrid(512, 5);
  paint_kernel<<<pgrid, 256, 0, stream>>>(pos, mask, out);
}